// Round 12
// baseline (137.409 us; speedup 1.0000x reference)
//
#include <hip/hip_runtime.h>

typedef unsigned short u16;
typedef __attribute__((ext_vector_type(8))) short short8;
typedef __attribute__((ext_vector_type(4))) float floatx4;

#define AS1 __attribute__((address_space(1)))
#define AS3 __attribute__((address_space(3)))

__device__ __forceinline__ u16 f2bf(float f) {
  unsigned u = __float_as_uint(f);
  u += 0x7fffu + ((u >> 16) & 1u);
  return (u16)(u >> 16);
}

// ---- prep (compacted): 1024 blocks; block pb computes gn partials for tile
// pb AND (pb<768) converts weight row pb into tiled wqkv; block 1023 also
// converts the 768 bias values.
__global__ void prep(const float* __restrict__ Wq, const float* __restrict__ Wk,
                     const float* __restrict__ Wv, const float* __restrict__ bq,
                     const float* __restrict__ bk, const float* __restrict__ bv,
                     u16* __restrict__ wqkv, float* __restrict__ bqkv,
                     const float* __restrict__ x, float* __restrict__ partials) {
  int pb = blockIdx.x, t = threadIdx.x;   // pb 0..1023
  if (pb < 768) {
    const float* src = pb < 256 ? Wq + pb * 256
                     : pb < 512 ? Wk + (pb - 256) * 256
                                : Wv + (pb - 512) * 256;
    wqkv[(size_t)(pb >> 7) * 32768 + (t >> 3) * 1024 + (pb & 127) * 8 + (t & 7)] =
        f2bf(src[t]);
  } else if (pb == 1023) {
    for (int i = 0; i < 3; ++i) {
      int d = i * 256 + t;
      float v = d < 256 ? bq[d] : d < 512 ? bk[d - 256] : bv[d - 512];
      bqkv[d] = v;
    }
  }
  int g = pb >> 4, part = pb & 15;
  const float4* b4 = (const float4*)(x + (size_t)g * 65536 + part * 4096);
  float s = 0.f, s2 = 0.f;
  for (int i = 0; i < 4; ++i) {
    float4 v = b4[i * 256 + t];
    s += v.x + v.y + v.z + v.w;
    s2 += v.x * v.x + v.y * v.y + v.z * v.z + v.w * v.w;
  }
  for (int off = 32; off; off >>= 1) {
    s += __shfl_xor(s, off);
    s2 += __shfl_xor(s2, off);
  }
  __shared__ float red[8];
  int wave = t >> 6, lane = t & 63;
  if (lane == 0) { red[wave] = s; red[4 + wave] = s2; }
  __syncthreads();
  if (t == 0) {
    partials[pb * 2]     = red[0] + red[1] + red[2] + red[3];
    partials[pb * 2 + 1] = red[4] + red[5] + red[6] + red[7];
  }
}

// ------- groupnorm apply + transpose: h tiled [b][pt 8][kc 32][row 128][e 8]
__global__ void gn_apply(const float* __restrict__ x, const float* __restrict__ gamma,
                         const float* __restrict__ beta, const float* __restrict__ partials,
                         u16* __restrict__ h) {
  __shared__ float tile[64][65];
  __shared__ float s_stats[2];
  int p0 = blockIdx.x * 64, c0 = blockIdx.y * 64, b = blockIdx.z;
  int t = threadIdx.x;
  int g = b * 4 + blockIdx.y;
  if (t < 16) {
    float s  = partials[(g * 16 + t) * 2];
    float s2 = partials[(g * 16 + t) * 2 + 1];
    for (int off = 8; off; off >>= 1) {
      s += __shfl_xor(s, off, 16);
      s2 += __shfl_xor(s2, off, 16);
    }
    if (t == 0) {
      float mean = s * (1.f / 65536.f);
      float var = s2 * (1.f / 65536.f) - mean * mean;
      s_stats[0] = mean;
      s_stats[1] = rsqrtf(var + 1e-5f);
    }
  }
  __syncthreads();
  float mean = s_stats[0], rstd = s_stats[1];
  int cl = t >> 4, p4 = t & 15;
  for (int i = 0; i < 4; ++i) {
    int c = cl + i * 16;
    float gm = gamma[c0 + c] * rstd;
    float bt = beta[c0 + c] - mean * gm;
    float4 v = *(const float4*)(x + ((size_t)(b * 256 + c0 + c)) * 1024 + p0 + p4 * 4);
    tile[c][p4 * 4 + 0] = v.x * gm + bt;
    tile[c][p4 * 4 + 1] = v.y * gm + bt;
    tile[c][p4 * 4 + 2] = v.z * gm + bt;
    tile[c][p4 * 4 + 3] = v.w * gm + bt;
  }
  __syncthreads();
  int c8 = t >> 5, pr = t & 31;   // c8 0..7, pr 0..31
  for (int i = 0; i < 2; ++i) {
    int p = pr + i * 32;
    union { u16 us[8]; uint4 v4; } tmp;
    for (int j = 0; j < 8; ++j) tmp.us[j] = f2bf(tile[c8 * 8 + j][p]);
    int pg = p0 + p;
    size_t idx = (size_t)b * 262144 + (size_t)(pg >> 7) * 32768 +
                 (size_t)((c0 >> 3) + c8) * 1024 + (size_t)(pg & 127) * 8;
    *(uint4*)(h + idx) = tmp.v4;
  }
}

// ------- QKV GEMM v3b: coalesced tiled staging; Q now stored TILED too ------
// o0 (Q) layout changed to [b][mt 16][kc 32][row 64][e 8] (= flash's fragment
// image, same form as K) so flash's Q prologue loads are coalesced instead of
// a 512B-lane-stride gather.
__global__ __launch_bounds__(512) void gemm_qkv(
    const u16* __restrict__ A, const u16* __restrict__ B,
    const float* __restrict__ bias,
    u16* __restrict__ o0, u16* __restrict__ o1, u16* __restrict__ o2) {
  __shared__ u16 As[4 * 128 * 8];  // 8 KB, chunk-major [kc 4][row 128][8]
  __shared__ u16 Bs[4 * 128 * 8];  // 8 KB
  int b = blockIdx.z;
  int m0 = blockIdx.x * 128, n0 = blockIdx.y * 128;
  const u16* Ab = A + (size_t)b * 262144 + (size_t)blockIdx.x * 32768;
  const u16* Bb = B + (size_t)blockIdx.y * 32768;
  int t = threadIdx.x, w = t >> 6, lane = t & 63;
  int q = lane >> 4, r16 = lane & 15;
  int wm = w & 1, wn = w >> 1;     // wave tile: 64 rows x 32 cols

  floatx4 acc[4][2];
#pragma unroll
  for (int i = 0; i < 4; ++i)
#pragma unroll
    for (int j = 0; j < 2; ++j) acc[i][j] = (floatx4)0.f;

  for (int ks = 0; ks < 8; ++ks) {
    size_t src = (size_t)(ks * 4 + (w >> 1)) * 1024 + (size_t)(w & 1) * 512 + lane * 8;
    __syncthreads();
    __builtin_amdgcn_global_load_lds((const AS1 void*)(Ab + src),
                                     (AS3 void*)(As + (size_t)w * 512), 16, 0, 0);
    __builtin_amdgcn_global_load_lds((const AS1 void*)(Bb + src),
                                     (AS3 void*)(Bs + (size_t)w * 512), 16, 0, 0);
    __syncthreads();
    short8 af[4], bfr[2];
#pragma unroll
    for (int mi = 0; mi < 4; ++mi)
      af[mi] = *(const short8*)(As + (size_t)(q * 128 + wm * 64 + mi * 16 + r16) * 8);
#pragma unroll
    for (int ni = 0; ni < 2; ++ni)
      bfr[ni] = *(const short8*)(Bs + (size_t)(q * 128 + wn * 32 + ni * 16 + r16) * 8);
#pragma unroll
    for (int mi = 0; mi < 4; ++mi)
#pragma unroll
      for (int ni = 0; ni < 2; ++ni)
        acc[mi][ni] = __builtin_amdgcn_mfma_f32_16x16x32_bf16(af[mi], bfr[ni], acc[mi][ni], 0, 0, 0);
  }

#pragma unroll
  for (int ni = 0; ni < 2; ++ni) {
    int dcol = n0 + wn * 32 + ni * 16 + r16;
    float bv_ = bias[dcol];
#pragma unroll
    for (int mi = 0; mi < 4; ++mi)
#pragma unroll
      for (int rg = 0; rg < 4; ++rg) {
        int mrow = m0 + wm * 64 + mi * 16 + q * 4 + rg;
        u16 hv = f2bf(acc[mi][ni][rg] + bv_);
        if (dcol < 256) {
          // Q tiled: [b][mt 16][kc 32][row 64][e 8]
          o0[(size_t)b * 262144 + (size_t)(mrow >> 6) * 16384 +
             (size_t)(dcol >> 3) * 512 + (mrow & 63) * 8 + (dcol & 7)] = hv;
        } else if (dcol < 512) {
          int c = dcol - 256;  // K tiled: [b][jt 16][kc 32][key 64][e 8]
          o1[(size_t)b * 262144 + (size_t)(mrow >> 6) * 16384 +
             (size_t)(c >> 3) * 512 + (mrow & 63) * 8 + (c & 7)] = hv;
        } else {
          int d = dcol - 512;  // V tiled: [b][jt 16][jc 8][d 256][e 8]
          o2[(size_t)b * 262144 + (size_t)(mrow >> 6) * 16384 +
             (size_t)((mrow >> 3) & 7) * 2048 + (size_t)d * 8 + (mrow & 7)] = hv;
        }
      }
  }
}

// ---- fused flash attention v13: v12 + coalesced tiled Q prologue loads -----
__global__ __launch_bounds__(512) void flash_attn(
    const u16* __restrict__ qb, const u16* __restrict__ kb,
    const u16* __restrict__ vT, const float* __restrict__ xres,
    float* __restrict__ outf) {
  __shared__ __align__(16) char smem[74240];
  u16* Ks = (u16*)smem;                       // [c-chunk 32][key 64][8] 32 KB
  u16* Vs = (u16*)(smem + 32768);             // [j-chunk 8][d 256][8]   32 KB
  u16* Ps = (u16*)(smem + 65536);             // [j-chunk 8][qrow 64][8]  8 KB
  float* lpart = (float*)(smem + 73728);      // [2][64]
  int idx = blockIdx.x;
  int b = (idx & 7) | ((idx >> 7) << 3);   // XCD swizzle: batch -> one XCD
  int qt = (idx >> 3) & 15;
  int m0 = qt * 64;
  int t = threadIdx.x, w = t >> 6, lane = t & 63;
  int q = lane >> 4, r16 = lane & 15;
  int wq = w & 3;       // S-phase row-group
  int kh = w >> 2;      // S-phase key-half
  const u16* Qb = qb + (size_t)b * 262144 + (size_t)qt * 16384;  // tiled Q
  const u16* Kb = kb + (size_t)b * 262144;
  const u16* Vb = vT + (size_t)b * 262144;

#pragma unroll
  for (int i = 0; i < 4; ++i)
    __builtin_amdgcn_global_load_lds(
        (const AS1 void*)(Kb + (size_t)(i * 8 + w) * 512 + lane * 8),
        (AS3 void*)(Ks + (size_t)(i * 8 + w) * 512), 16, 0, 0);

  short8 qf[8];
#pragma unroll
  for (int ks = 0; ks < 8; ++ks)   // tiled: 16 lanes = 256B contiguous
    qf[ks] = *(const short8*)(Qb + ((size_t)(ks * 4 + q) * 64 + wq * 16 + r16) * 8);

  __syncthreads();  // K(0) landed

  float l_acc[4] = {0.f, 0.f, 0.f, 0.f};
  floatx4 acc_o[4][2];
#pragma unroll
  for (int i = 0; i < 4; ++i)
#pragma unroll
    for (int j = 0; j < 2; ++j) acc_o[i][j] = (floatx4)0.f;

  const float cexp = 0.0625f * 1.44269504f;

  for (int jt = 0; jt < 16; ++jt) {
#pragma unroll
    for (int i = 0; i < 4; ++i)
      __builtin_amdgcn_global_load_lds(
          (const AS1 void*)(Vb + (size_t)jt * 16384 + (size_t)(i * 8 + w) * 512 + lane * 8),
          (AS3 void*)(Vs + (size_t)(i * 8 + w) * 512), 16, 0, 0);

    floatx4 acc_s[2];
    acc_s[0] = (floatx4)0.f;
    acc_s[1] = (floatx4)0.f;
#pragma unroll
    for (int ks = 0; ks < 8; ++ks) {
#pragma unroll
      for (int ni = 0; ni < 2; ++ni) {
        short8 bf = *(const short8*)(Ks + (size_t)((ks * 4 + q) * 64 + kh * 32 + ni * 16 + r16) * 8);
        acc_s[ni] = __builtin_amdgcn_mfma_f32_16x16x32_bf16(qf[ks], bf, acc_s[ni], 0, 0, 0);
      }
    }

#pragma unroll
    for (int ni = 0; ni < 2; ++ni)
#pragma unroll
      for (int rg = 0; rg < 4; ++rg) {
        float p = exp2f(acc_s[ni][rg] * cexp);
        l_acc[rg] += p;
        int jc = kh * 4 + ni * 2 + (r16 >> 3);
        Ps[(size_t)(jc * 64 + wq * 16 + q * 4 + rg) * 8 + (r16 & 7)] = f2bf(p);
      }

    __syncthreads();  // mid: V(jt)+Ps visible; Ks(jt) reads done

    if (jt < 15) {
#pragma unroll
      for (int i = 0; i < 4; ++i)
        __builtin_amdgcn_global_load_lds(
            (const AS1 void*)(Kb + (size_t)(jt + 1) * 16384 + (size_t)(i * 8 + w) * 512 + lane * 8),
            (AS3 void*)(Ks + (size_t)(i * 8 + w) * 512), 16, 0, 0);
    }

#pragma unroll
    for (int ks2 = 0; ks2 < 2; ++ks2) {
      short8 af[4];
#pragma unroll
      for (int mi = 0; mi < 4; ++mi)
        af[mi] = *(const short8*)(Ps + (size_t)((ks2 * 4 + q) * 64 + mi * 16 + r16) * 8);
#pragma unroll
      for (int ni2 = 0; ni2 < 2; ++ni2) {
        short8 bf = *(const short8*)(Vs + (size_t)((ks2 * 4 + q) * 256 + w * 32 + ni2 * 16 + r16) * 8);
#pragma unroll
        for (int mi = 0; mi < 4; ++mi)
          acc_o[mi][ni2] = __builtin_amdgcn_mfma_f32_16x16x32_bf16(af[mi], bf, acc_o[mi][ni2], 0, 0, 0);
      }
    }
    __syncthreads();  // end: K(jt+1) landed; Vs/Ps reads done
  }

#pragma unroll
  for (int rg = 0; rg < 4; ++rg) {
    float l = l_acc[rg];
    l += __shfl_xor(l, 1);
    l += __shfl_xor(l, 2);
    l += __shfl_xor(l, 4);
    l += __shfl_xor(l, 8);
    if (r16 == 0) lpart[kh * 64 + wq * 16 + q * 4 + rg] = l;
  }
  __syncthreads();  // lpart ready; all Ks/Vs reads done -> otile may alias

  // ---- coalesced epilogue: d-major write to padded LDS, p-major read ----
  float* otile = (float*)smem;   // [128][68] f32 = 34.8 KB (aliases Ks+Vs)
#pragma unroll
  for (int half = 0; half < 2; ++half) {
    if ((w >> 2) == half) {
#pragma unroll
      for (int mi = 0; mi < 4; ++mi) {
        float iv[4];
#pragma unroll
        for (int rg = 0; rg < 4; ++rg) {
          int row = mi * 16 + q * 4 + rg;
          iv[rg] = 1.f / (lpart[row] + lpart[64 + row]);
        }
#pragma unroll
        for (int ni2 = 0; ni2 < 2; ++ni2) {
          int dl = (w & 3) * 32 + ni2 * 16 + r16;   // d - half*128
          float4 o;
          o.x = acc_o[mi][ni2][0] * iv[0];
          o.y = acc_o[mi][ni2][1] * iv[1];
          o.z = acc_o[mi][ni2][2] * iv[2];
          o.w = acc_o[mi][ni2][3] * iv[3];
          *(float4*)(otile + (size_t)dl * 68 + mi * 16 + q * 4) = o;
        }
      }
    }
    __syncthreads();  // half-tile written
#pragma unroll
    for (int dp = 0; dp < 4; ++dp) {
      int dl = dp * 32 + (t >> 4);
      int p = (t & 15) * 4;
      float4 ov = *(const float4*)(otile + (size_t)dl * 68 + p);
      size_t go = ((size_t)b * 256 + half * 128 + dl) * 1024 + m0 + p;
      float4 xv = *(const float4*)(xres + go);
      float4 oo;
      oo.x = ov.x + xv.x;
      oo.y = ov.y + xv.y;
      oo.z = ov.z + xv.z;
      oo.w = ov.w + xv.w;
      *(float4*)(outf + go) = oo;
    }
    __syncthreads();  // reads done before next half overwrites
  }
}

extern "C" void kernel_launch(void* const* d_in, const int* in_sizes, int n_in,
                              void* d_out, int out_size, void* d_ws, size_t ws_size,
                              hipStream_t stream) {
  (void)in_sizes; (void)n_in; (void)out_size; (void)ws_size;
  const float* x     = (const float*)d_in[0];
  const float* Wq    = (const float*)d_in[1];
  const float* bq    = (const float*)d_in[2];
  const float* Wk    = (const float*)d_in[3];
  const float* bk    = (const float*)d_in[4];
  const float* Wv    = (const float*)d_in[5];
  const float* bv    = (const float*)d_in[6];
  const float* gamma = (const float*)d_in[7];
  const float* beta  = (const float*)d_in[8];
  float* out = (float*)d_out;
  char* ws = (char*)d_ws;

  u16*   h      = (u16*)(ws);                                  // 8 MiB
  u16*   wqkv   = (u16*)(ws + (8u << 20));                     // 384 KiB
  float* bqkv   = (float*)(ws + (8u << 20) + (384u << 10));    // 3 KiB
  float* statsP = (float*)(ws + (8u << 20) + (400u << 10));    // 8 KiB
  u16*   qb     = (u16*)(ws + (9u << 20));                     // 8 MiB
  u16*   kb     = (u16*)(ws + (17u << 20));                    // 8 MiB
  u16*   vT     = (u16*)(ws + (25u << 20));                    // 8 MiB

  hipLaunchKernelGGL(prep, dim3(1024), dim3(256), 0, stream,
                     Wq, Wk, Wv, bq, bk, bv, wqkv, bqkv, x, statsP);
  hipLaunchKernelGGL(gn_apply, dim3(16, 4, 16), dim3(256), 0, stream,
                     x, gamma, beta, statsP, h);
  hipLaunchKernelGGL(gemm_qkv, dim3(8, 6, 16), dim3(512), 0, stream,
                     h, wqkv, bqkv, qb, kb, vT);
  hipLaunchKernelGGL(flash_attn, dim3(256), dim3(512), 0, stream, qb, kb, vT, x, out);
}

// Round 13
// 133.130 us; speedup vs baseline: 1.0321x; 1.0321x over previous
//
#include <hip/hip_runtime.h>

typedef unsigned short u16;
typedef __attribute__((ext_vector_type(8))) short short8;
typedef __attribute__((ext_vector_type(4))) float floatx4;

#define AS1 __attribute__((address_space(1)))
#define AS3 __attribute__((address_space(3)))

__device__ __forceinline__ u16 f2bf(float f) {
  unsigned u = __float_as_uint(f);
  u += 0x7fffu + ((u >> 16) & 1u);
  return (u16)(u >> 16);
}

// ---- prep (compacted): 1024 blocks; block pb computes gn partials for tile
// pb AND (pb<768) converts weight row pb into tiled wqkv; block 1023 also
// converts the 768 bias values.
__global__ void prep(const float* __restrict__ Wq, const float* __restrict__ Wk,
                     const float* __restrict__ Wv, const float* __restrict__ bq,
                     const float* __restrict__ bk, const float* __restrict__ bv,
                     u16* __restrict__ wqkv, float* __restrict__ bqkv,
                     const float* __restrict__ x, float* __restrict__ partials) {
  int pb = blockIdx.x, t = threadIdx.x;   // pb 0..1023
  if (pb < 768) {
    const float* src = pb < 256 ? Wq + pb * 256
                     : pb < 512 ? Wk + (pb - 256) * 256
                                : Wv + (pb - 512) * 256;
    wqkv[(size_t)(pb >> 7) * 32768 + (t >> 3) * 1024 + (pb & 127) * 8 + (t & 7)] =
        f2bf(src[t]);
  } else if (pb == 1023) {
    for (int i = 0; i < 3; ++i) {
      int d = i * 256 + t;
      float v = d < 256 ? bq[d] : d < 512 ? bk[d - 256] : bv[d - 512];
      bqkv[d] = v;
    }
  }
  int g = pb >> 4, part = pb & 15;
  const float4* b4 = (const float4*)(x + (size_t)g * 65536 + part * 4096);
  float s = 0.f, s2 = 0.f;
  for (int i = 0; i < 4; ++i) {
    float4 v = b4[i * 256 + t];
    s += v.x + v.y + v.z + v.w;
    s2 += v.x * v.x + v.y * v.y + v.z * v.z + v.w * v.w;
  }
  for (int off = 32; off; off >>= 1) {
    s += __shfl_xor(s, off);
    s2 += __shfl_xor(s2, off);
  }
  __shared__ float red[8];
  int wave = t >> 6, lane = t & 63;
  if (lane == 0) { red[wave] = s; red[4 + wave] = s2; }
  __syncthreads();
  if (t == 0) {
    partials[pb * 2]     = red[0] + red[1] + red[2] + red[3];
    partials[pb * 2 + 1] = red[4] + red[5] + red[6] + red[7];
  }
}

// ------- groupnorm apply + transpose: h tiled [b][pt 8][kc 32][row 128][e 8]
__global__ void gn_apply(const float* __restrict__ x, const float* __restrict__ gamma,
                         const float* __restrict__ beta, const float* __restrict__ partials,
                         u16* __restrict__ h) {
  __shared__ float tile[64][65];
  __shared__ float s_stats[2];
  int p0 = blockIdx.x * 64, c0 = blockIdx.y * 64, b = blockIdx.z;
  int t = threadIdx.x;
  int g = b * 4 + blockIdx.y;
  if (t < 16) {
    float s  = partials[(g * 16 + t) * 2];
    float s2 = partials[(g * 16 + t) * 2 + 1];
    for (int off = 8; off; off >>= 1) {
      s += __shfl_xor(s, off, 16);
      s2 += __shfl_xor(s2, off, 16);
    }
    if (t == 0) {
      float mean = s * (1.f / 65536.f);
      float var = s2 * (1.f / 65536.f) - mean * mean;
      s_stats[0] = mean;
      s_stats[1] = rsqrtf(var + 1e-5f);
    }
  }
  __syncthreads();
  float mean = s_stats[0], rstd = s_stats[1];
  int cl = t >> 4, p4 = t & 15;
  for (int i = 0; i < 4; ++i) {
    int c = cl + i * 16;
    float gm = gamma[c0 + c] * rstd;
    float bt = beta[c0 + c] - mean * gm;
    float4 v = *(const float4*)(x + ((size_t)(b * 256 + c0 + c)) * 1024 + p0 + p4 * 4);
    tile[c][p4 * 4 + 0] = v.x * gm + bt;
    tile[c][p4 * 4 + 1] = v.y * gm + bt;
    tile[c][p4 * 4 + 2] = v.z * gm + bt;
    tile[c][p4 * 4 + 3] = v.w * gm + bt;
  }
  __syncthreads();
  int c8 = t >> 5, pr = t & 31;   // c8 0..7, pr 0..31
  for (int i = 0; i < 2; ++i) {
    int p = pr + i * 32;
    union { u16 us[8]; uint4 v4; } tmp;
    for (int j = 0; j < 8; ++j) tmp.us[j] = f2bf(tile[c8 * 8 + j][p]);
    int pg = p0 + p;
    size_t idx = (size_t)b * 262144 + (size_t)(pg >> 7) * 32768 +
                 (size_t)((c0 >> 3) + c8) * 1024 + (size_t)(pg & 127) * 8;
    *(uint4*)(h + idx) = tmp.v4;
  }
}

// ---------------- QKV GEMM v3 (R3/R10-measured): coalesced tiled staging ----
__global__ __launch_bounds__(512) void gemm_qkv(
    const u16* __restrict__ A, const u16* __restrict__ B,
    const float* __restrict__ bias,
    u16* __restrict__ o0, u16* __restrict__ o1, u16* __restrict__ o2) {
  __shared__ u16 As[4 * 128 * 8];  // 8 KB, chunk-major [kc 4][row 128][8]
  __shared__ u16 Bs[4 * 128 * 8];  // 8 KB
  int b = blockIdx.z;
  int m0 = blockIdx.x * 128, n0 = blockIdx.y * 128;
  const u16* Ab = A + (size_t)b * 262144 + (size_t)blockIdx.x * 32768;
  const u16* Bb = B + (size_t)blockIdx.y * 32768;
  int t = threadIdx.x, w = t >> 6, lane = t & 63;
  int q = lane >> 4, r16 = lane & 15;
  int wm = w & 1, wn = w >> 1;     // wave tile: 64 rows x 32 cols

  floatx4 acc[4][2];
#pragma unroll
  for (int i = 0; i < 4; ++i)
#pragma unroll
    for (int j = 0; j < 2; ++j) acc[i][j] = (floatx4)0.f;

  for (int ks = 0; ks < 8; ++ks) {
    size_t src = (size_t)(ks * 4 + (w >> 1)) * 1024 + (size_t)(w & 1) * 512 + lane * 8;
    __syncthreads();
    __builtin_amdgcn_global_load_lds((const AS1 void*)(Ab + src),
                                     (AS3 void*)(As + (size_t)w * 512), 16, 0, 0);
    __builtin_amdgcn_global_load_lds((const AS1 void*)(Bb + src),
                                     (AS3 void*)(Bs + (size_t)w * 512), 16, 0, 0);
    __syncthreads();
    short8 af[4], bfr[2];
#pragma unroll
    for (int mi = 0; mi < 4; ++mi)
      af[mi] = *(const short8*)(As + (size_t)(q * 128 + wm * 64 + mi * 16 + r16) * 8);
#pragma unroll
    for (int ni = 0; ni < 2; ++ni)
      bfr[ni] = *(const short8*)(Bs + (size_t)(q * 128 + wn * 32 + ni * 16 + r16) * 8);
#pragma unroll
    for (int mi = 0; mi < 4; ++mi)
#pragma unroll
      for (int ni = 0; ni < 2; ++ni)
        acc[mi][ni] = __builtin_amdgcn_mfma_f32_16x16x32_bf16(af[mi], bfr[ni], acc[mi][ni], 0, 0, 0);
  }

#pragma unroll
  for (int ni = 0; ni < 2; ++ni) {
    int dcol = n0 + wn * 32 + ni * 16 + r16;
    float bv_ = bias[dcol];
#pragma unroll
    for (int mi = 0; mi < 4; ++mi)
#pragma unroll
      for (int rg = 0; rg < 4; ++rg) {
        int mrow = m0 + wm * 64 + mi * 16 + q * 4 + rg;
        u16 hv = f2bf(acc[mi][ni][rg] + bv_);
        if (dcol < 256) {
          o0[((size_t)b * 1024 + mrow) * 256 + dcol] = hv;
        } else if (dcol < 512) {
          int c = dcol - 256;  // K tiled: [b][jt 16][kc 32][key 64][e 8]
          o1[(size_t)b * 262144 + (size_t)(mrow >> 6) * 16384 +
             (size_t)(c >> 3) * 512 + (mrow & 63) * 8 + (c & 7)] = hv;
        } else {
          int d = dcol - 512;  // V tiled: [b][jt 16][jc 8][d 256][e 8]
          o2[(size_t)b * 262144 + (size_t)(mrow >> 6) * 16384 +
             (size_t)((mrow >> 3) & 7) * 2048 + (size_t)d * 8 + (mrow & 7)] = hv;
        }
      }
  }
}

// -------- fused flash attention v12 (R11-measured, champion): v7 loop + -----
// coalesced LDS-transpose epilogue.
__global__ __launch_bounds__(512) void flash_attn(
    const u16* __restrict__ qb, const u16* __restrict__ kb,
    const u16* __restrict__ vT, const float* __restrict__ xres,
    float* __restrict__ outf) {
  __shared__ __align__(16) char smem[74240];
  u16* Ks = (u16*)smem;                       // [c-chunk 32][key 64][8] 32 KB
  u16* Vs = (u16*)(smem + 32768);             // [j-chunk 8][d 256][8]   32 KB
  u16* Ps = (u16*)(smem + 65536);             // [j-chunk 8][qrow 64][8]  8 KB
  float* lpart = (float*)(smem + 73728);      // [2][64]
  int idx = blockIdx.x;
  int b = (idx & 7) | ((idx >> 7) << 3);   // XCD swizzle: batch -> one XCD
  int qt = (idx >> 3) & 15;
  int m0 = qt * 64;
  int t = threadIdx.x, w = t >> 6, lane = t & 63;
  int q = lane >> 4, r16 = lane & 15;
  int wq = w & 3;       // S-phase row-group
  int kh = w >> 2;      // S-phase key-half
  const u16* Qb = qb + ((size_t)b * 1024 + m0) * 256;
  const u16* Kb = kb + (size_t)b * 262144;
  const u16* Vb = vT + (size_t)b * 262144;

#pragma unroll
  for (int i = 0; i < 4; ++i)
    __builtin_amdgcn_global_load_lds(
        (const AS1 void*)(Kb + (size_t)(i * 8 + w) * 512 + lane * 8),
        (AS3 void*)(Ks + (size_t)(i * 8 + w) * 512), 16, 0, 0);

  short8 qf[8];
#pragma unroll
  for (int ks = 0; ks < 8; ++ks)
    qf[ks] = *(const short8*)(Qb + (size_t)(wq * 16 + r16) * 256 + ks * 32 + q * 8);

  __syncthreads();  // K(0) landed

  float l_acc[4] = {0.f, 0.f, 0.f, 0.f};
  floatx4 acc_o[4][2];
#pragma unroll
  for (int i = 0; i < 4; ++i)
#pragma unroll
    for (int j = 0; j < 2; ++j) acc_o[i][j] = (floatx4)0.f;

  const float cexp = 0.0625f * 1.44269504f;

  for (int jt = 0; jt < 16; ++jt) {
#pragma unroll
    for (int i = 0; i < 4; ++i)
      __builtin_amdgcn_global_load_lds(
          (const AS1 void*)(Vb + (size_t)jt * 16384 + (size_t)(i * 8 + w) * 512 + lane * 8),
          (AS3 void*)(Vs + (size_t)(i * 8 + w) * 512), 16, 0, 0);

    floatx4 acc_s[2];
    acc_s[0] = (floatx4)0.f;
    acc_s[1] = (floatx4)0.f;
#pragma unroll
    for (int ks = 0; ks < 8; ++ks) {
#pragma unroll
      for (int ni = 0; ni < 2; ++ni) {
        short8 bf = *(const short8*)(Ks + (size_t)((ks * 4 + q) * 64 + kh * 32 + ni * 16 + r16) * 8);
        acc_s[ni] = __builtin_amdgcn_mfma_f32_16x16x32_bf16(qf[ks], bf, acc_s[ni], 0, 0, 0);
      }
    }

#pragma unroll
    for (int ni = 0; ni < 2; ++ni)
#pragma unroll
      for (int rg = 0; rg < 4; ++rg) {
        float p = exp2f(acc_s[ni][rg] * cexp);
        l_acc[rg] += p;
        int jc = kh * 4 + ni * 2 + (r16 >> 3);
        Ps[(size_t)(jc * 64 + wq * 16 + q * 4 + rg) * 8 + (r16 & 7)] = f2bf(p);
      }

    __syncthreads();  // mid: V(jt)+Ps visible; Ks(jt) reads done

    if (jt < 15) {
#pragma unroll
      for (int i = 0; i < 4; ++i)
        __builtin_amdgcn_global_load_lds(
            (const AS1 void*)(Kb + (size_t)(jt + 1) * 16384 + (size_t)(i * 8 + w) * 512 + lane * 8),
            (AS3 void*)(Ks + (size_t)(i * 8 + w) * 512), 16, 0, 0);
    }

#pragma unroll
    for (int ks2 = 0; ks2 < 2; ++ks2) {
      short8 af[4];
#pragma unroll
      for (int mi = 0; mi < 4; ++mi)
        af[mi] = *(const short8*)(Ps + (size_t)((ks2 * 4 + q) * 64 + mi * 16 + r16) * 8);
#pragma unroll
      for (int ni2 = 0; ni2 < 2; ++ni2) {
        short8 bf = *(const short8*)(Vs + (size_t)((ks2 * 4 + q) * 256 + w * 32 + ni2 * 16 + r16) * 8);
#pragma unroll
        for (int mi = 0; mi < 4; ++mi)
          acc_o[mi][ni2] = __builtin_amdgcn_mfma_f32_16x16x32_bf16(af[mi], bf, acc_o[mi][ni2], 0, 0, 0);
      }
    }
    __syncthreads();  // end: K(jt+1) landed; Vs/Ps reads done
  }

#pragma unroll
  for (int rg = 0; rg < 4; ++rg) {
    float l = l_acc[rg];
    l += __shfl_xor(l, 1);
    l += __shfl_xor(l, 2);
    l += __shfl_xor(l, 4);
    l += __shfl_xor(l, 8);
    if (r16 == 0) lpart[kh * 64 + wq * 16 + q * 4 + rg] = l;
  }
  __syncthreads();  // lpart ready; all Ks/Vs reads done -> otile may alias

  // ---- coalesced epilogue: d-major write to padded LDS, p-major read ----
  float* otile = (float*)smem;   // [128][68] f32 = 34.8 KB (aliases Ks+Vs)
#pragma unroll
  for (int half = 0; half < 2; ++half) {
    if ((w >> 2) == half) {
#pragma unroll
      for (int mi = 0; mi < 4; ++mi) {
        float iv[4];
#pragma unroll
        for (int rg = 0; rg < 4; ++rg) {
          int row = mi * 16 + q * 4 + rg;
          iv[rg] = 1.f / (lpart[row] + lpart[64 + row]);
        }
#pragma unroll
        for (int ni2 = 0; ni2 < 2; ++ni2) {
          int dl = (w & 3) * 32 + ni2 * 16 + r16;   // d - half*128
          float4 o;
          o.x = acc_o[mi][ni2][0] * iv[0];
          o.y = acc_o[mi][ni2][1] * iv[1];
          o.z = acc_o[mi][ni2][2] * iv[2];
          o.w = acc_o[mi][ni2][3] * iv[3];
          *(float4*)(otile + (size_t)dl * 68 + mi * 16 + q * 4) = o;
        }
      }
    }
    __syncthreads();  // half-tile written
#pragma unroll
    for (int dp = 0; dp < 4; ++dp) {
      int dl = dp * 32 + (t >> 4);
      int p = (t & 15) * 4;
      float4 ov = *(const float4*)(otile + (size_t)dl * 68 + p);
      size_t go = ((size_t)b * 256 + half * 128 + dl) * 1024 + m0 + p;
      float4 xv = *(const float4*)(xres + go);
      float4 oo;
      oo.x = ov.x + xv.x;
      oo.y = ov.y + xv.y;
      oo.z = ov.z + xv.z;
      oo.w = ov.w + xv.w;
      *(float4*)(outf + go) = oo;
    }
    __syncthreads();  // reads done before next half overwrites
  }
}

extern "C" void kernel_launch(void* const* d_in, const int* in_sizes, int n_in,
                              void* d_out, int out_size, void* d_ws, size_t ws_size,
                              hipStream_t stream) {
  (void)in_sizes; (void)n_in; (void)out_size; (void)ws_size;
  const float* x     = (const float*)d_in[0];
  const float* Wq    = (const float*)d_in[1];
  const float* bq    = (const float*)d_in[2];
  const float* Wk    = (const float*)d_in[3];
  const float* bk    = (const float*)d_in[4];
  const float* Wv    = (const float*)d_in[5];
  const float* bv    = (const float*)d_in[6];
  const float* gamma = (const float*)d_in[7];
  const float* beta  = (const float*)d_in[8];
  float* out = (float*)d_out;
  char* ws = (char*)d_ws;

  u16*   h      = (u16*)(ws);                                  // 8 MiB
  u16*   wqkv   = (u16*)(ws + (8u << 20));                     // 384 KiB
  float* bqkv   = (float*)(ws + (8u << 20) + (384u << 10));    // 3 KiB
  float* statsP = (float*)(ws + (8u << 20) + (400u << 10));    // 8 KiB
  u16*   qb     = (u16*)(ws + (9u << 20));                     // 8 MiB
  u16*   kb     = (u16*)(ws + (17u << 20));                    // 8 MiB
  u16*   vT     = (u16*)(ws + (25u << 20));                    // 8 MiB

  hipLaunchKernelGGL(prep, dim3(1024), dim3(256), 0, stream,
                     Wq, Wk, Wv, bq, bk, bv, wqkv, bqkv, x, statsP);
  hipLaunchKernelGGL(gn_apply, dim3(16, 4, 16), dim3(256), 0, stream,
                     x, gamma, beta, statsP, h);
  hipLaunchKernelGGL(gemm_qkv, dim3(8, 6, 16), dim3(512), 0, stream,
                     h, wqkv, bqkv, qb, kb, vT);
  hipLaunchKernelGGL(flash_attn, dim3(256), dim3(512), 0, stream, qb, kb, vT, x, out);
}